// Round 5
// baseline (4515.766 us; speedup 1.0000x reference)
//
#include <hip/hip_runtime.h>
#include <math.h>

// Problem constants (B, T, D_IN, D_OUT) = (64, 1024, 512, 512)
#define BATCH   64
#define TSTEPS  1024
#define DIN     512
#define DH      512
#define MDIM    (BATCH * TSTEPS)

// ---- K2 (MFMA scan) geometry ----
// 4 wgs x 512 threads (8 waves each); wg owns MB=16 batches, wave owns 64 cols.
// Wr (fp16, transposed to [col][k]) residency per wave:
//   col-slices 0..2 (48 cols) -> B-frags in VGPR/AGPR (192 regs)
//   col-slice  3   (16 cols)  -> streamed from L2 via global_load (VMEM pipe)
// H[16][512] fp16 in LDS, DOUBLE-buffered -> ONE barrier/step.
#define MB     16
#define HSTR   260                    // words per H row: 256 + 4 pad (stride==4 mod 32)
#define HBUF_W (16 * HSTR)            // 4160 words = 16.64 KB per buffer

typedef _Float16 f16x8 __attribute__((ext_vector_type(8)));
typedef float    f32x4 __attribute__((ext_vector_type(4)));

__device__ inline unsigned short f2h_bits(float x) {
    _Float16 h = (_Float16)x;
    return __builtin_bit_cast(unsigned short, h);
}
// fast tanh: 1 - 2/(exp2(2x*log2e)+1); saturates correctly incl. +-inf
__device__ inline float ftanh(float x) {
    float e = __builtin_amdgcn_exp2f(x * 2.88539008177792681472f);
    return 1.0f - 2.0f * __builtin_amdgcn_rcpf(e + 1.0f);
}

// ---------------------------------------------------------------------------
// K1a: convert x (fp32) -> Xh (fp16)
// ---------------------------------------------------------------------------
__global__ __launch_bounds__(256) void convert_x(const float* __restrict__ x,
                                                 _Float16* __restrict__ xh,
                                                 int nvec) {
    int i = blockIdx.x * blockDim.x + threadIdx.x;
    int stride = gridDim.x * blockDim.x;
    for (; i < nvec; i += stride) {
        const float4* p = (const float4*)x + 2 * (size_t)i;
        float4 a = p[0], b = p[1];
        f16x8 o = { (_Float16)a.x, (_Float16)a.y, (_Float16)a.z, (_Float16)a.w,
                    (_Float16)b.x, (_Float16)b.y, (_Float16)b.z, (_Float16)b.w };
        ((f16x8*)xh)[i] = o;
    }
}

// ---------------------------------------------------------------------------
// K1b: Out[n][k] = (fp16) In[k][n]   (512x512) — used for both W and Wr
// ---------------------------------------------------------------------------
__global__ __launch_bounds__(256) void transpose_w(const float* __restrict__ In,
                                                   _Float16* __restrict__ Out) {
    __shared__ float tile[64][65];
    const int t  = threadIdx.x;
    const int c  = t & 63;
    const int r0 = t >> 6;
    const int bn = blockIdx.x & 7;
    const int bk = blockIdx.x >> 3;
    const int k0 = bk * 64, n0 = bn * 64;
    #pragma unroll
    for (int i = 0; i < 16; ++i)
        tile[r0 + 4 * i][c] = In[(size_t)(k0 + r0 + 4 * i) * DH + n0 + c];
    __syncthreads();
    #pragma unroll
    for (int i = 0; i < 16; ++i)
        Out[(size_t)(n0 + r0 + 4 * i) * DIN + k0 + c] = (_Float16)tile[c][r0 + 4 * i];
}

// ---------------------------------------------------------------------------
// K1c: XWh = fp16( Xh @ Wt^T + bias )  via mfma_f32_16x16x32_f16
// (validated r2-r4; epilogue now stores fp16)
// ---------------------------------------------------------------------------
__global__ __launch_bounds__(256) void gemm_xw_mfma(const _Float16* __restrict__ Xh,
                                                    const _Float16* __restrict__ Wt,
                                                    const float* __restrict__ bias,
                                                    _Float16* __restrict__ XWh) {
    __shared__ __align__(16) _Float16 Ah[128][32];
    __shared__ __align__(16) _Float16 Bh[128][32];

    const int tid  = threadIdx.x;
    const int wv   = tid >> 6;
    const int lane = tid & 63;
    const int bn   = blockIdx.x & 3;
    const int bm   = blockIdx.x >> 2;
    const int m0   = bm * 128;
    const int n0   = bn * 128;

    const int mbase = (wv >> 1) * 64;
    const int nbase = (wv & 1) * 64;
    const int fr    = lane & 15;
    const int fq    = lane >> 4;

    f32x4 acc[4][4];
    #pragma unroll
    for (int i = 0; i < 4; ++i)
        #pragma unroll
        for (int j = 0; j < 4; ++j)
            acc[i][j] = (f32x4){0.f, 0.f, 0.f, 0.f};

    for (int kc = 0; kc < DIN / 32; ++kc) {
        const int k0 = kc * 32;
#if __has_builtin(__builtin_amdgcn_global_load_lds)
        #pragma unroll
        for (int q = 0; q < 2; ++q) {
            const int rb = wv * 2 + q;
            const int gr = (rb * 16) + (lane >> 2);
            const int gc = (lane & 3) * 8;
            const _Float16* ga = Xh + (size_t)(m0 + gr) * DIN + k0 + gc;
            const _Float16* gb = Wt + (size_t)(n0 + gr) * DIN + k0 + gc;
            __builtin_amdgcn_global_load_lds(
                (const __attribute__((address_space(1))) void*)ga,
                (__attribute__((address_space(3))) void*)&Ah[rb * 16][0], 16, 0, 0);
            __builtin_amdgcn_global_load_lds(
                (const __attribute__((address_space(1))) void*)gb,
                (__attribute__((address_space(3))) void*)&Bh[rb * 16][0], 16, 0, 0);
        }
#else
        #pragma unroll
        for (int q = 0; q < 2; ++q) {
            const int h0 = (q * 256 + tid) * 8;
            const int row = h0 >> 5, col = h0 & 31;
            *((uint4*)Ah + (q * 256 + tid)) =
                *(const uint4*)(Xh + (size_t)(m0 + row) * DIN + k0 + col);
            *((uint4*)Bh + (q * 256 + tid)) =
                *(const uint4*)(Wt + (size_t)(n0 + row) * DIN + k0 + col);
        }
#endif
        __syncthreads();

        f16x8 af[4], bf[4];
        #pragma unroll
        for (int mt = 0; mt < 4; ++mt)
            af[mt] = *(const f16x8*)&Ah[mbase + mt * 16 + fr][fq * 8];
        #pragma unroll
        for (int nt = 0; nt < 4; ++nt)
            bf[nt] = *(const f16x8*)&Bh[nbase + nt * 16 + fr][fq * 8];
        #pragma unroll
        for (int mt = 0; mt < 4; ++mt)
            #pragma unroll
            for (int nt = 0; nt < 4; ++nt)
                acc[mt][nt] = __builtin_amdgcn_mfma_f32_16x16x32_f16(
                    af[mt], bf[nt], acc[mt][nt], 0, 0, 0);
        __syncthreads();
    }

    #pragma unroll
    for (int nt = 0; nt < 4; ++nt) {
        const int col = n0 + nbase + nt * 16 + fr;
        const float bvl = bias[col];
        #pragma unroll
        for (int mt = 0; mt < 4; ++mt) {
            #pragma unroll
            for (int r = 0; r < 4; ++r) {
                const int row = m0 + mbase + mt * 16 + fq * 4 + r;
                XWh[(size_t)row * DH + col] = (_Float16)(acc[mt][nt][r] + bvl);
            }
        }
    }
}

// ---------------------------------------------------------------------------
// K2: batch-stacked MFMA scan, v5.
//  - LDS holds ONLY H (double buffer, 2x16.64 KB) -> 128 ds_read_b128 +
//    128 ds_write_b16 per wg-step, ONE barrier/step.
//  - Wr B-frags: slices 0..2 resident in regs; slice 3 streamed from L2
//    (WrT fp16 [col][k], 16B-contiguous per frag) on the VMEM pipe.
// Fragment layouts identical to r4 (validated):
//   A: lane(fr,fq) holds H[m=fr][k=32c+8fq+j]
//   B: lane(fr,fq) holds Wr[k=32c+8fq+j][col=base+fr]
//   C: lane(fr,fq) holds D[m=4fq+r][col=base+fr]
// ---------------------------------------------------------------------------
__global__ __launch_bounds__(512, 2) void rnn_scan5(const _Float16* __restrict__ XWh,
                                                    const _Float16* __restrict__ WrT,
                                                    float* __restrict__ Hout) {
    __shared__ unsigned int hb[2 * HBUF_W];

    const int tid  = threadIdx.x;
    const int wv   = tid >> 6;        // wave 0..7 -> cols [wv*64, wv*64+64)
    const int lane = tid & 63;
    const int fr   = lane & 15;
    const int fq   = lane >> 4;
    const int b0   = blockIdx.x * MB;

    // ---- one-time: B-frags for col-slices 0..2 -> registers (192 regs) ----
    f16x8 breg[3][16];
    #pragma unroll
    for (int s = 0; s < 3; ++s) {
        const _Float16* pb = WrT + (size_t)(wv * 64 + s * 16 + fr) * DIN + fq * 8;
        #pragma unroll
        for (int c = 0; c < 16; ++c)
            breg[s][c] = *(const f16x8*)(pb + c * 32);
    }
    // streamed slice-3 base (constant address set, L2-resident)
    const _Float16* p3 = WrT + (size_t)(wv * 64 + 48 + fr) * DIN + fq * 8;

    // zero both H buffers (h0 = 0)
    for (int i = tid; i < 2 * HBUF_W; i += 512) hb[i] = 0u;
    __syncthreads();

    const _Float16* xwp = XWh + (size_t)(b0 + fq * 4) * TSTEPS * DH + wv * 64 + fr;
    const unsigned int* ab0 = hb + fr * HSTR + fq * 4;
    const unsigned int* ab1 = ab0 + HBUF_W;

    int cur = 0;
    #pragma unroll 1
    for (int t = 0; t < TSTEPS; ++t) {
        const unsigned int* ab = cur ? ab1 : ab0;

        // xw for this step (consumed ~2000 cyc later; latency hidden)
        float xv[4][4];
        #pragma unroll
        for (int s = 0; s < 4; ++s)
            #pragma unroll
            for (int r = 0; r < 4; ++r)
                xv[s][r] = (float)xwp[(size_t)r * TSTEPS * DH + (size_t)t * DH + s * 16];

        f32x4 cc[4];
        #pragma unroll
        for (int s = 0; s < 4; ++s) cc[s] = (f32x4){0.f, 0.f, 0.f, 0.f};

        // software-pipelined slice-3 stream (depth 2)
        f16x8 bcur = *(const f16x8*)(p3 + 0 * 32);
        f16x8 bnxt = *(const f16x8*)(p3 + 1 * 32);

        #pragma unroll
        for (int c = 0; c < 16; ++c) {
            f16x8 af = __builtin_bit_cast(f16x8, *(const uint4*)(ab + c * 16));
            cc[0] = __builtin_amdgcn_mfma_f32_16x16x32_f16(af, breg[0][c], cc[0], 0, 0, 0);
            cc[1] = __builtin_amdgcn_mfma_f32_16x16x32_f16(af, breg[1][c], cc[1], 0, 0, 0);
            cc[2] = __builtin_amdgcn_mfma_f32_16x16x32_f16(af, breg[2][c], cc[2], 0, 0, 0);
            cc[3] = __builtin_amdgcn_mfma_f32_16x16x32_f16(af, bcur,       cc[3], 0, 0, 0);
            bcur = bnxt;
            if (c + 2 < 16) bnxt = *(const f16x8*)(p3 + (c + 2) * 32);
        }

        // epilogue: h = tanh(acc + xw) -> fp16 into the OTHER buffer
        unsigned short* hn = (unsigned short*)(hb + (cur ^ 1) * HBUF_W);
        #pragma unroll
        for (int s = 0; s < 4; ++s) {
            #pragma unroll
            for (int r = 0; r < 4; ++r) {
                float h = ftanh(cc[s][r] + xv[s][r]);
                hn[(fq * 4 + r) * (HSTR * 2) + wv * 64 + s * 16 + fr] = f2h_bits(h);
            }
        }
        __syncthreads();   // writes to nxt visible; all waves done with cur
        cur ^= 1;
    }

    // final H is in buffer `cur` (cur==0 after 1024 flips)
    {
        const unsigned short* hf = (const unsigned short*)(hb + cur * HBUF_W);
        const int m  = tid >> 5;
        const int cb = (tid & 31) * 16;
        #pragma unroll
        for (int g = 0; g < 16; g += 8) {
            f16x8 v = __builtin_bit_cast(f16x8,
                *(const uint4*)(hf + (size_t)m * (HSTR * 2) + cb + g));
            float4 o0 = { (float)v[0], (float)v[1], (float)v[2], (float)v[3] };
            float4 o1 = { (float)v[4], (float)v[5], (float)v[6], (float)v[7] };
            *(float4*)&Hout[(size_t)(b0 + m) * DH + cb + g]     = o0;
            *(float4*)&Hout[(size_t)(b0 + m) * DH + cb + g + 4] = o1;
        }
    }
}

// ---------------------------------------------------------------------------
// launch
// ---------------------------------------------------------------------------
extern "C" void kernel_launch(void* const* d_in, const int* in_sizes, int n_in,
                              void* d_out, int out_size, void* d_ws, size_t ws_size,
                              hipStream_t stream) {
    const float* x  = (const float*)d_in[0];
    const float* W  = (const float*)d_in[1];
    const float* Wr = (const float*)d_in[2];
    const float* bv = (const float*)d_in[3];
    float* out = (float*)d_out;

    const size_t XWH_BYTES = (size_t)MDIM * DH * sizeof(_Float16);   // 67.1 MB
    const size_t XH_BYTES  = (size_t)MDIM * DIN * sizeof(_Float16);  // 67.1 MB
    const size_t WT_BYTES  = (size_t)DIN * DH * sizeof(_Float16);    //  0.5 MB
    if (ws_size < XWH_BYTES + XH_BYTES + 2 * WT_BYTES) return;

    _Float16* xwh = (_Float16*)d_ws;
    _Float16* xh  = (_Float16*)((char*)d_ws + XWH_BYTES);
    _Float16* wt  = (_Float16*)((char*)d_ws + XWH_BYTES + XH_BYTES);
    _Float16* wrt = (_Float16*)((char*)d_ws + XWH_BYTES + XH_BYTES + WT_BYTES);

    convert_x<<<dim3(2048), dim3(256), 0, stream>>>(x, xh, MDIM * DIN / 8);
    transpose_w<<<dim3(64), dim3(256), 0, stream>>>(W, wt);
    transpose_w<<<dim3(64), dim3(256), 0, stream>>>(Wr, wrt);
    gemm_xw_mfma<<<dim3((MDIM / 128) * (DH / 128)), dim3(256), 0, stream>>>(
        xh, wt, bv, xwh);
    rnn_scan5<<<dim3(BATCH / MB), dim3(512), 0, stream>>>(xwh, wrt, out);
}